// Round 8
// baseline (264.912 us; speedup 1.0000x reference)
//
#include <hip/hip_runtime.h>
#include <hip/hip_fp16.h>
#include <math.h>

#define F_IN   256
#define C1     128   // H1*D1
#define H1N    4
#define D2N    64

#define SCAN_T    256
#define SCAN_TILE 512   // 2 elements per thread

#define BK1 32          // gemm1 K-tile

// ---------------- utility ----------------
__global__ void zero_ints(int* p, int n) {
    int i = blockIdx.x * blockDim.x + threadIdx.x;
    for (; i < n; i += gridDim.x * blockDim.x) p[i] = 0;
}

// ---------------- layer 1 GEMM: hx1 = x @ W1 (fp16 out, + attention logits) ----------------
// Register-tiled: BM=64, BN=128, BK=32; 256 threads; per-thread 8 rows x 4 cols.
// Software-pipelined: tile k+1's global loads issue before tile k's FMA block,
// so HBM latency hides under the 2048-cycle compute instead of stalling the LDS write.
__global__ __launch_bounds__(256) void gemm1_kernel(
        const float* __restrict__ x, const float* __restrict__ W1,
        const float* __restrict__ attS, const float* __restrict__ attD,
        __half* __restrict__ hx1h, float* __restrict__ as1, float* __restrict__ ad1,
        int N) {
    __shared__ float xT[BK1][64 + 4];
    __shared__ float ws[BK1][C1];

    int tid = threadIdx.x;
    int tx  = tid & 31;          // col group: cols tx*4 .. tx*4+3
    int ty  = tid >> 5;          // row group: rows ty*8 .. ty*8+7
    int n0  = blockIdx.x * 64;

    float acc[8][4];
#pragma unroll
    for (int r = 0; r < 8; ++r)
#pragma unroll
        for (int c = 0; c < 4; ++c) acc[r][c] = 0.f;

    int lr = tid >> 2;                 // 0..63
    int lk = (tid & 3) * 4;            // 0,4,8,12
    int xrow = n0 + lr; if (xrow >= N) xrow = N - 1;   // clamp (stores are guarded)
    const float* xptr = x + (size_t)xrow * F_IN;
    int kw = ty;
    int cw = tx * 4;

    // prologue: load tile 0 into registers
    float4 a0 = *(const float4*)(xptr + lk);
    float4 a1 = *(const float4*)(xptr + lk + 16);
    float4 w0 = *(const float4*)(W1 + (size_t)(kw     ) * C1 + cw);
    float4 w1 = *(const float4*)(W1 + (size_t)(kw +  8) * C1 + cw);
    float4 w2 = *(const float4*)(W1 + (size_t)(kw + 16) * C1 + cw);
    float4 w3 = *(const float4*)(W1 + (size_t)(kw + 24) * C1 + cw);

    for (int k0 = 0; k0 < F_IN; k0 += BK1) {
        __syncthreads();               // previous tile fully consumed
        xT[lk + 0][lr] = a0.x; xT[lk + 1][lr] = a0.y;
        xT[lk + 2][lr] = a0.z; xT[lk + 3][lr] = a0.w;
        xT[lk + 16][lr] = a1.x; xT[lk + 17][lr] = a1.y;
        xT[lk + 18][lr] = a1.z; xT[lk + 19][lr] = a1.w;
        *(float4*)&ws[kw     ][cw] = w0;
        *(float4*)&ws[kw +  8][cw] = w1;
        *(float4*)&ws[kw + 16][cw] = w2;
        *(float4*)&ws[kw + 24][cw] = w3;
        __syncthreads();
        int kn = k0 + BK1;
        if (kn < F_IN) {               // issue next tile's loads; first use is next
            a0 = *(const float4*)(xptr + kn + lk);            // iteration's LDS write,
            a1 = *(const float4*)(xptr + kn + lk + 16);       // so latency hides under
            w0 = *(const float4*)(W1 + (size_t)(kn + kw     ) * C1 + cw);  // the FMAs below
            w1 = *(const float4*)(W1 + (size_t)(kn + kw +  8) * C1 + cw);
            w2 = *(const float4*)(W1 + (size_t)(kn + kw + 16) * C1 + cw);
            w3 = *(const float4*)(W1 + (size_t)(kn + kw + 24) * C1 + cw);
        }
#pragma unroll
        for (int k = 0; k < BK1; ++k) {
            float4 xa = *(const float4*)&xT[k][ty * 8];
            float4 xb = *(const float4*)&xT[k][ty * 8 + 4];
            float4 wv = *(const float4*)&ws[k][tx * 4];
            float xr[8] = {xa.x, xa.y, xa.z, xa.w, xb.x, xb.y, xb.z, xb.w};
            float wc[4] = {wv.x, wv.y, wv.z, wv.w};
#pragma unroll
            for (int r = 0; r < 8; ++r)
#pragma unroll
                for (int c = 0; c < 4; ++c) acc[r][c] += xr[r] * wc[c];
        }
    }

    const float4 asv = *(const float4*)(attS + tx * 4);
    const float4 adv = *(const float4*)(attD + tx * 4);
    int h = tx >> 3;
#pragma unroll
    for (int r = 0; r < 8; ++r) {
        int n = n0 + ty * 8 + r;
        float ts = acc[r][0] * asv.x + acc[r][1] * asv.y + acc[r][2] * asv.z + acc[r][3] * asv.w;
        float td = acc[r][0] * adv.x + acc[r][1] * adv.y + acc[r][2] * adv.z + acc[r][3] * adv.w;
        ts += __shfl_xor(ts, 1); td += __shfl_xor(td, 1);
        ts += __shfl_xor(ts, 2); td += __shfl_xor(td, 2);
        ts += __shfl_xor(ts, 4); td += __shfl_xor(td, 4);
        if (n < N) {
            __half2 p01 = __floats2half2_rn(acc[r][0], acc[r][1]);
            __half2 p23 = __floats2half2_rn(acc[r][2], acc[r][3]);
            *(__half2*)&hx1h[(size_t)n * C1 + tx * 4]     = p01;
            *(__half2*)&hx1h[(size_t)n * C1 + tx * 4 + 2] = p23;
            if ((tx & 7) == 0) {
                as1[n * H1N + h] = ts;
                ad1[n * H1N + h] = td;
            }
        }
    }
}

// ---------------- CSR build ----------------
__global__ void count_kernel(const int* __restrict__ dst, int* __restrict__ counts, int E) {
    int i = blockIdx.x * blockDim.x + threadIdx.x;
    for (; i < E; i += gridDim.x * blockDim.x) atomicAdd(&counts[dst[i]], 1);
}

__global__ void scan_partial(const int* __restrict__ counts, int* __restrict__ tilesums, int N) {
    __shared__ int red[SCAN_T];
    int t  = threadIdx.x;
    int i0 = blockIdx.x * SCAN_TILE + 2 * t;
    int s = 0;
    if (i0     < N) s += counts[i0];
    if (i0 + 1 < N) s += counts[i0 + 1];
    red[t] = s;
    __syncthreads();
    for (int off = SCAN_T / 2; off > 0; off >>= 1) {
        if (t < off) red[t] += red[t + off];
        __syncthreads();
    }
    if (t == 0) tilesums[blockIdx.x] = red[0];
}

__global__ void scan_tops(const int* __restrict__ tilesums, int* __restrict__ tilebase, int ntiles) {
    __shared__ int sh[SCAN_T];
    int t = threadIdx.x;
    int v = (t < ntiles) ? tilesums[t] : 0;
    sh[t] = v;
    __syncthreads();
    for (int off = 1; off < SCAN_T; off <<= 1) {
        int u = (t >= off) ? sh[t - off] : 0;
        __syncthreads();
        sh[t] += u;
        __syncthreads();
    }
    tilebase[t] = sh[t] - v;
}

__global__ void scan_final(const int* __restrict__ counts, const int* __restrict__ tilebase,
                           int* __restrict__ offsets, int* __restrict__ cursor, int N, int E) {
    __shared__ int sh[SCAN_T];
    int t  = threadIdx.x;
    int i0 = blockIdx.x * SCAN_TILE + 2 * t;
    int a   = (i0     < N) ? counts[i0]     : 0;
    int b   = (i0 + 1 < N) ? counts[i0 + 1] : 0;
    int tot = a + b;
    sh[t] = tot;
    __syncthreads();
    for (int off = 1; off < SCAN_T; off <<= 1) {
        int u = (t >= off) ? sh[t - off] : 0;
        __syncthreads();
        sh[t] += u;
        __syncthreads();
    }
    int excl = sh[t] - tot + tilebase[blockIdx.x];
    if (i0 < N)     { offsets[i0]     = excl;     cursor[i0]     = excl; }
    if (i0 + 1 < N) { offsets[i0 + 1] = excl + a; cursor[i0 + 1] = excl + a; }
    if (blockIdx.x == 0 && t == 0) offsets[N] = E;
}

// XCD-binned scatter: block group (blockIdx&7) presumed to live on one XCD and
// owns dst range [N*g/8, N*(g+1)/8). Correctness does NOT depend on the mapping.
__global__ void scatter_xcd(const int* __restrict__ src, const int* __restrict__ dst,
                            int* __restrict__ cursor, int* __restrict__ edge_src,
                            int E, int N) {
    int grp  = blockIdx.x & 7;
    int gidx = blockIdx.x >> 3;
    int ngrp = gridDim.x >> 3;
    int lo = (int)((long long)N * grp / 8);
    int hi = (int)((long long)N * (grp + 1) / 8);
    for (int i = gidx * blockDim.x + threadIdx.x; i < E; i += ngrp * blockDim.x) {
        int d = dst[i];
        if (d >= lo && d < hi) {
            int p = atomicAdd(&cursor[d], 1);
            edge_src[p] = src[i];
        }
    }
}

// ---------------- layer 1 aggregate: one wave per dst node, fp16 gather ----------------
// lane owns adjacent cols (2l, 2l+1) -> one half2 per edge; both cols in head l>>4.
__global__ void agg1_kernel(const int* __restrict__ edge_src, const int* __restrict__ offsets,
                            const float* __restrict__ as1, const float* __restrict__ ad1,
                            const __half* __restrict__ hx1h, const float* __restrict__ b1,
                            float* __restrict__ x1, int N) {
    __shared__ int   ssh[4][64];
    __shared__ float esh[4][64][4];
    int wid  = threadIdx.x >> 6;
    int n    = (blockIdx.x * blockDim.x + threadIdx.x) >> 6;
    int lane = threadIdx.x & 63;
    if (n >= N) return;
    int hsel = lane >> 4;                    // head of cols (2l, 2l+1)
    const float4 ad4 = *(const float4*)(ad1 + 4 * n);
    int beg = offsets[n], end = offsets[n + 1];

    float m[4]   = {-INFINITY, -INFINITY, -INFINITY, -INFINITY};
    float den[4] = {0.f, 0.f, 0.f, 0.f};
    float acc0 = 0.f, acc1 = 0.f;

    for (int cb = beg; cb < end; cb += 64) {
        int j = cb + lane;
        bool valid = j < end;
        int s = valid ? edge_src[j] : 0;
        float e[4];
        if (valid) {
            const float4 a4 = *(const float4*)(as1 + 4 * s);
            e[0] = a4.x + ad4.x; e[1] = a4.y + ad4.y;
            e[2] = a4.z + ad4.z; e[3] = a4.w + ad4.w;
#pragma unroll
            for (int h = 0; h < 4; ++h) e[h] = e[h] > 0.f ? e[h] : 0.2f * e[h];
        } else {
#pragma unroll
            for (int h = 0; h < 4; ++h) e[h] = -INFINITY;
        }
        float cm[4];
#pragma unroll
        for (int h = 0; h < 4; ++h) cm[h] = e[h];
#pragma unroll
        for (int off = 32; off > 0; off >>= 1)
#pragma unroll
            for (int h = 0; h < 4; ++h) cm[h] = fmaxf(cm[h], __shfl_xor(cm[h], off, 64));
        float scale[4];
#pragma unroll
        for (int h = 0; h < 4; ++h) {
            float nm = fmaxf(m[h], cm[h]);
            scale[h] = __expf(m[h] - nm);
            m[h] = nm;
            den[h] *= scale[h];
        }
        float sc = lane < 16 ? scale[0] : lane < 32 ? scale[1] : lane < 48 ? scale[2] : scale[3];
        acc0 *= sc; acc1 *= sc;
        float t[4];
#pragma unroll
        for (int h = 0; h < 4; ++h) {
            e[h] = valid ? __expf(e[h] - m[h]) : 0.f;
            t[h] = e[h];
        }
#pragma unroll
        for (int off = 32; off > 0; off >>= 1)
#pragma unroll
            for (int h = 0; h < 4; ++h) t[h] += __shfl_xor(t[h], off, 64);
#pragma unroll
        for (int h = 0; h < 4; ++h) den[h] += t[h];

        ssh[wid][lane] = s;
        *(float4*)&esh[wid][lane][0] = make_float4(e[0], e[1], e[2], e[3]);

        int cnt = min(64, end - cb);
#pragma unroll 2
        for (int jj = 0; jj < cnt; ++jj) {
            int   sj = ssh[wid][jj];
            float w  = esh[wid][jj][hsel];
            const __half2* hr = (const __half2*)(hx1h + (size_t)sj * C1);
            float2 vf = __half22float2(hr[lane]);
            acc0 += w * vf.x;
            acc1 += w * vf.y;
        }
    }

    float d = lane < 16 ? den[0] : lane < 32 ? den[1] : lane < 48 ? den[2] : den[3];
    float inv = 1.f / (d + 1e-16f);
    float2 bv = *(const float2*)(b1 + 2 * lane);
    float o0 = acc0 * inv + bv.x;
    float o1 = acc1 * inv + bv.y;
    o0 = o0 > 0.f ? o0 : (__expf(o0) - 1.f);   // ELU
    o1 = o1 > 0.f ? o1 : (__expf(o1) - 1.f);
    *(float2*)&x1[(size_t)n * C1 + 2 * lane] = make_float2(o0, o1);
}

// ---------------- layer 2 GEMM: hx2 = x1 @ W2, + logits ----------------
__global__ void gemm2_kernel(const float* __restrict__ x1, const float* __restrict__ W2,
                             const float* __restrict__ attS, const float* __restrict__ attD,
                             float* __restrict__ hx2, float* __restrict__ as2, float* __restrict__ ad2,
                             int N) {
    const int ROWS = 4;
    __shared__ float xs[ROWS][C1];
    int d  = threadIdx.x;
    int n0 = blockIdx.x * ROWS;
    for (int r = 0; r < ROWS; ++r) {
        int n = n0 + r;
        for (int k = d; k < C1; k += 64)
            xs[r][k] = (n < N) ? x1[(size_t)n * C1 + k] : 0.f;
    }
    __syncthreads();
    float acc[ROWS] = {0.f, 0.f, 0.f, 0.f};
    for (int k = 0; k < C1; ++k) {
        float w = W2[k * D2N + d];
#pragma unroll
        for (int r = 0; r < ROWS; ++r) acc[r] += xs[r][k] * w;
    }
    float a_s = attS[d], a_d = attD[d];
    for (int r = 0; r < ROWS; ++r) {
        int n = n0 + r;
        if (n >= N) break;
        float v = acc[r];
        hx2[(size_t)n * D2N + d] = v;
        float ts = v * a_s, td = v * a_d;
        for (int off = 32; off > 0; off >>= 1) {
            ts += __shfl_xor(ts, off, 64);
            td += __shfl_xor(td, off, 64);
        }
        if (d == 0) { as2[n] = ts; ad2[n] = td; }
    }
}

// ---------------- layer 2 aggregate: only last num_new nodes ----------------
__global__ void agg2_kernel(const int* __restrict__ edge_src, const int* __restrict__ offsets,
                            const float* __restrict__ as2, const float* __restrict__ ad2,
                            const float* __restrict__ hx2, const float* __restrict__ b2,
                            float* __restrict__ out, int N, int num_new) {
    __shared__ int   ssh[4][64];
    __shared__ float esh[4][64];
    int wid  = threadIdx.x >> 6;
    int w    = (blockIdx.x * blockDim.x + threadIdx.x) >> 6;
    int lane = threadIdx.x & 63;
    if (w >= num_new) return;
    int n = N - num_new + w;
    float adn = ad2[n];
    int beg = offsets[n], end = offsets[n + 1];

    float m = -INFINITY, den = 0.f, acc = 0.f;
    for (int cb = beg; cb < end; cb += 64) {
        int j = cb + lane;
        bool valid = j < end;
        int s = valid ? edge_src[j] : 0;
        float v = valid ? (as2[s] + adn) : -INFINITY;
        if (valid) v = v > 0.f ? v : 0.2f * v;
        float cm = v;
#pragma unroll
        for (int off = 32; off > 0; off >>= 1) cm = fmaxf(cm, __shfl_xor(cm, off, 64));
        float nm = fmaxf(m, cm);
        float scale = __expf(m - nm);
        m = nm;
        den *= scale;
        acc *= scale;
        float e = valid ? __expf(v - m) : 0.f;
        float t = e;
#pragma unroll
        for (int off = 32; off > 0; off >>= 1) t += __shfl_xor(t, off, 64);
        den += t;

        ssh[wid][lane] = s;
        esh[wid][lane] = e;

        int cnt = min(64, end - cb);
#pragma unroll 2
        for (int jj = 0; jj < cnt; ++jj) {
            int   sj = ssh[wid][jj];
            float wj = esh[wid][jj];
            acc += wj * hx2[(size_t)sj * D2N + lane];
        }
    }
    out[(size_t)w * D2N + lane] = acc / (den + 1e-16f) + b2[lane];
}

// ---------------- launch ----------------
extern "C" void kernel_launch(void* const* d_in, const int* in_sizes, int n_in,
                              void* d_out, int out_size, void* d_ws, size_t ws_size,
                              hipStream_t stream) {
    const float* x      = (const float*)d_in[0];
    const int*   src    = (const int*)d_in[1];
    const int*   dst    = (const int*)d_in[2];
    const float* W1     = (const float*)d_in[3];
    const float* attS1  = (const float*)d_in[4];
    const float* attD1  = (const float*)d_in[5];
    const float* b1     = (const float*)d_in[6];
    const float* W2     = (const float*)d_in[7];
    const float* attS2  = (const float*)d_in[8];
    const float* attD2  = (const float*)d_in[9];
    const float* b2     = (const float*)d_in[10];

    const int N = in_sizes[0] / F_IN;   // 50000
    const int E = in_sizes[1];          // 1000000
    const int num_new = out_size / D2N; // 10000
    const int ntiles = (N + SCAN_TILE - 1) / SCAN_TILE;   // 98

    // workspace carve-up
    __half* hx1h = (__half*)d_ws;                        // N*128 halves
    float* x1  = (float*)(hx1h + (size_t)N * C1);        // N*128 f32
    float* hx2 = x1  + (size_t)N * C1;                   // N*64
    float* as1 = hx2 + (size_t)N * D2N;                  // N*4
    float* ad1 = as1 + (size_t)N * H1N;                  // N*4
    float* as2 = ad1 + (size_t)N * H1N;                  // N
    float* ad2 = as2 + N;                                // N
    int* counts   = (int*)(ad2 + N);                     // N
    int* offsets  = counts + N;                          // N+1
    int* cursor   = offsets + N + 1;                     // N
    int* tilesums = cursor + N;                          // 256
    int* tilebase = tilesums + 256;                      // 256
    int* edge_src = tilebase + 256;                      // E

    float* out = (float*)d_out;

    hipLaunchKernelGGL(zero_ints, dim3(256), dim3(256), 0, stream, counts, N);
    hipLaunchKernelGGL(gemm1_kernel, dim3((N + 63) / 64), dim3(256), 0, stream,
                       x, W1, attS1, attD1, hx1h, as1, ad1, N);
    hipLaunchKernelGGL(count_kernel, dim3(2048), dim3(256), 0, stream, dst, counts, E);
    hipLaunchKernelGGL(scan_partial, dim3(ntiles), dim3(SCAN_T), 0, stream, counts, tilesums, N);
    hipLaunchKernelGGL(scan_tops, dim3(1), dim3(SCAN_T), 0, stream, tilesums, tilebase, ntiles);
    hipLaunchKernelGGL(scan_final, dim3(ntiles), dim3(SCAN_T), 0, stream,
                       counts, tilebase, offsets, cursor, N, E);
    hipLaunchKernelGGL(scatter_xcd, dim3(2048), dim3(256), 0, stream,
                       src, dst, cursor, edge_src, E, N);
    hipLaunchKernelGGL(agg1_kernel, dim3((N + 3) / 4), dim3(256), 0, stream,
                       edge_src, offsets, as1, ad1, hx1h, b1, x1, N);
    hipLaunchKernelGGL(gemm2_kernel, dim3((N + 3) / 4), dim3(64), 0, stream,
                       x1, W2, attS2, attD2, hx2, as2, ad2, N);
    hipLaunchKernelGGL(agg2_kernel, dim3((num_new + 3) / 4), dim3(256), 0, stream,
                       edge_src, offsets, as2, ad2, hx2, b2, out, N, num_new);
}

// Round 9
// 183.628 us; speedup vs baseline: 1.4427x; 1.4427x over previous
//
#include <hip/hip_runtime.h>
#include <hip/hip_fp16.h>
#include <math.h>

#define F_IN   256
#define C1     128   // H1*D1
#define H1N    4
#define D2N    64

#define SCAN_T    256
#define SCAN_TILE 512   // 2 elements per thread

#define BK1 32          // gemm K-tile

// ---------------- utility ----------------
__global__ void zero_ints(int* p, int n) {
    int i = blockIdx.x * blockDim.x + threadIdx.x;
    for (; i < n; i += gridDim.x * blockDim.x) p[i] = 0;
}

// ---------------- fused: layer-1 GEMM (blocks < ngemm) + edge count/rank (rest) ----------------
// GEMM: hx1 = x @ W1 (fp16 out, + attention logits). BM=64, BN=128, BK=32; 8x4 acc/thread.
// Count: edge_rank[i] = atomicAdd(counts[dst[i]], 1) — latency-bound, fills gemm's idle slots.
__global__ __launch_bounds__(256) void gemm1_count_kernel(
        const float* __restrict__ x, const float* __restrict__ W1,
        const float* __restrict__ attS, const float* __restrict__ attD,
        __half* __restrict__ hx1h, float* __restrict__ as1, float* __restrict__ ad1,
        int N,
        const int* __restrict__ dst, int* __restrict__ counts,
        int* __restrict__ edge_rank, int E, int ngemm) {
    if ((int)blockIdx.x >= ngemm) {
        int b  = blockIdx.x - ngemm;
        int nb = gridDim.x - ngemm;
        for (int i = b * blockDim.x + threadIdx.x; i < E; i += nb * blockDim.x)
            edge_rank[i] = atomicAdd(&counts[dst[i]], 1);
        return;
    }

    __shared__ float xT[BK1][64 + 4];
    __shared__ float ws[BK1][C1];

    int tid = threadIdx.x;
    int tx  = tid & 31;          // col group: cols tx*4 .. tx*4+3
    int ty  = tid >> 5;          // row group: rows ty*8 .. ty*8+7
    int n0  = blockIdx.x * 64;

    float acc[8][4];
#pragma unroll
    for (int r = 0; r < 8; ++r)
#pragma unroll
        for (int c = 0; c < 4; ++c) acc[r][c] = 0.f;

    int lr = tid >> 2;                 // 0..63
    int lk = (tid & 3) * 4;            // 0,4,8,12
    int xrow = n0 + lr; if (xrow >= N) xrow = N - 1;   // clamp (stores are guarded)
    const float* xptr = x + (size_t)xrow * F_IN;
    int kw = ty;
    int cw = tx * 4;

    for (int k0 = 0; k0 < F_IN; k0 += BK1) {
        float4 a0 = *(const float4*)(xptr + k0 + lk);
        float4 a1 = *(const float4*)(xptr + k0 + lk + 16);
        float4 w0 = *(const float4*)(W1 + (size_t)(k0 + kw     ) * C1 + cw);
        float4 w1 = *(const float4*)(W1 + (size_t)(k0 + kw +  8) * C1 + cw);
        float4 w2 = *(const float4*)(W1 + (size_t)(k0 + kw + 16) * C1 + cw);
        float4 w3 = *(const float4*)(W1 + (size_t)(k0 + kw + 24) * C1 + cw);
        __syncthreads();
        xT[lk + 0][lr] = a0.x; xT[lk + 1][lr] = a0.y;
        xT[lk + 2][lr] = a0.z; xT[lk + 3][lr] = a0.w;
        xT[lk + 16][lr] = a1.x; xT[lk + 17][lr] = a1.y;
        xT[lk + 18][lr] = a1.z; xT[lk + 19][lr] = a1.w;
        *(float4*)&ws[kw     ][cw] = w0;
        *(float4*)&ws[kw +  8][cw] = w1;
        *(float4*)&ws[kw + 16][cw] = w2;
        *(float4*)&ws[kw + 24][cw] = w3;
        __syncthreads();
#pragma unroll
        for (int k = 0; k < BK1; ++k) {
            float4 xa = *(const float4*)&xT[k][ty * 8];
            float4 xb = *(const float4*)&xT[k][ty * 8 + 4];
            float4 wv = *(const float4*)&ws[k][tx * 4];
            float xr[8] = {xa.x, xa.y, xa.z, xa.w, xb.x, xb.y, xb.z, xb.w};
            float wc[4] = {wv.x, wv.y, wv.z, wv.w};
#pragma unroll
            for (int r = 0; r < 8; ++r)
#pragma unroll
                for (int c = 0; c < 4; ++c) acc[r][c] += xr[r] * wc[c];
        }
    }

    const float4 asv = *(const float4*)(attS + tx * 4);
    const float4 adv = *(const float4*)(attD + tx * 4);
    int h = tx >> 3;
#pragma unroll
    for (int r = 0; r < 8; ++r) {
        int n = n0 + ty * 8 + r;
        float ts = acc[r][0] * asv.x + acc[r][1] * asv.y + acc[r][2] * asv.z + acc[r][3] * asv.w;
        float td = acc[r][0] * adv.x + acc[r][1] * adv.y + acc[r][2] * adv.z + acc[r][3] * adv.w;
        ts += __shfl_xor(ts, 1); td += __shfl_xor(td, 1);
        ts += __shfl_xor(ts, 2); td += __shfl_xor(td, 2);
        ts += __shfl_xor(ts, 4); td += __shfl_xor(td, 4);
        if (n < N) {
            __half2 p01 = __floats2half2_rn(acc[r][0], acc[r][1]);
            __half2 p23 = __floats2half2_rn(acc[r][2], acc[r][3]);
            *(__half2*)&hx1h[(size_t)n * C1 + tx * 4]     = p01;
            *(__half2*)&hx1h[(size_t)n * C1 + tx * 4 + 2] = p23;
            if ((tx & 7) == 0) {
                as1[n * H1N + h] = ts;
                ad1[n * H1N + h] = td;
            }
        }
    }
}

// ---------------- scan: counts -> offsets ----------------
__global__ void scan_partial(const int* __restrict__ counts, int* __restrict__ tilesums, int N) {
    __shared__ int red[SCAN_T];
    int t  = threadIdx.x;
    int i0 = blockIdx.x * SCAN_TILE + 2 * t;
    int s = 0;
    if (i0     < N) s += counts[i0];
    if (i0 + 1 < N) s += counts[i0 + 1];
    red[t] = s;
    __syncthreads();
    for (int off = SCAN_T / 2; off > 0; off >>= 1) {
        if (t < off) red[t] += red[t + off];
        __syncthreads();
    }
    if (t == 0) tilesums[blockIdx.x] = red[0];
}

__global__ void scan_tops(const int* __restrict__ tilesums, int* __restrict__ tilebase, int ntiles) {
    __shared__ int sh[SCAN_T];
    int t = threadIdx.x;
    int v = (t < ntiles) ? tilesums[t] : 0;
    sh[t] = v;
    __syncthreads();
    for (int off = 1; off < SCAN_T; off <<= 1) {
        int u = (t >= off) ? sh[t - off] : 0;
        __syncthreads();
        sh[t] += u;
        __syncthreads();
    }
    tilebase[t] = sh[t] - v;
}

__global__ void scan_final(const int* __restrict__ counts, const int* __restrict__ tilebase,
                           int* __restrict__ offsets, int N, int E) {
    __shared__ int sh[SCAN_T];
    int t  = threadIdx.x;
    int i0 = blockIdx.x * SCAN_TILE + 2 * t;
    int a   = (i0     < N) ? counts[i0]     : 0;
    int b   = (i0 + 1 < N) ? counts[i0 + 1] : 0;
    int tot = a + b;
    sh[t] = tot;
    __syncthreads();
    for (int off = 1; off < SCAN_T; off <<= 1) {
        int u = (t >= off) ? sh[t - off] : 0;
        __syncthreads();
        sh[t] += u;
        __syncthreads();
    }
    int excl = sh[t] - tot + tilebase[blockIdx.x];
    if (i0 < N)     offsets[i0]     = excl;
    if (i0 + 1 < N) offsets[i0 + 1] = excl + a;
    if (blockIdx.x == 0 && t == 0) offsets[N] = E;
}

// ---------------- atomic-free, XCD-binned scatter ----------------
// position = offsets[dst] + rank (rank precomputed in the fused count).
// Block group (blockIdx&7) owns dst range [N*g/8, N*(g+1)/8): writes confined
// to ~500KB so lines merge in one XCD's L2. Mapping is perf-only, not correctness.
__global__ void scatter_rank(const int* __restrict__ src, const int* __restrict__ dst,
                             const int* __restrict__ edge_rank, const int* __restrict__ offsets,
                             int* __restrict__ edge_src, int E, int N) {
    int grp  = blockIdx.x & 7;
    int gidx = blockIdx.x >> 3;
    int ngrp = gridDim.x >> 3;
    int lo = (int)((long long)N * grp / 8);
    int hi = (int)((long long)N * (grp + 1) / 8);
    for (int i = gidx * blockDim.x + threadIdx.x; i < E; i += ngrp * blockDim.x) {
        int d = dst[i];
        if (d >= lo && d < hi)
            edge_src[offsets[d] + edge_rank[i]] = src[i];
    }
}

// ---------------- layer 1 aggregate: one wave per dst node, fp16 gather ----------------
__global__ void agg1_kernel(const int* __restrict__ edge_src, const int* __restrict__ offsets,
                            const float* __restrict__ as1, const float* __restrict__ ad1,
                            const __half* __restrict__ hx1h, const float* __restrict__ b1,
                            float* __restrict__ x1, int N) {
    __shared__ int   ssh[4][64];
    __shared__ float esh[4][64][4];
    int wid  = threadIdx.x >> 6;
    int n    = (blockIdx.x * blockDim.x + threadIdx.x) >> 6;
    int lane = threadIdx.x & 63;
    if (n >= N) return;
    int hsel = lane >> 4;                    // head of cols (2l, 2l+1)
    const float4 ad4 = *(const float4*)(ad1 + 4 * n);
    int beg = offsets[n], end = offsets[n + 1];

    float m[4]   = {-INFINITY, -INFINITY, -INFINITY, -INFINITY};
    float den[4] = {0.f, 0.f, 0.f, 0.f};
    float acc0 = 0.f, acc1 = 0.f;

    for (int cb = beg; cb < end; cb += 64) {
        int j = cb + lane;
        bool valid = j < end;
        int s = valid ? edge_src[j] : 0;
        float e[4];
        if (valid) {
            const float4 a4 = *(const float4*)(as1 + 4 * s);
            e[0] = a4.x + ad4.x; e[1] = a4.y + ad4.y;
            e[2] = a4.z + ad4.z; e[3] = a4.w + ad4.w;
#pragma unroll
            for (int h = 0; h < 4; ++h) e[h] = e[h] > 0.f ? e[h] : 0.2f * e[h];
        } else {
#pragma unroll
            for (int h = 0; h < 4; ++h) e[h] = -INFINITY;
        }
        float cm[4];
#pragma unroll
        for (int h = 0; h < 4; ++h) cm[h] = e[h];
#pragma unroll
        for (int off = 32; off > 0; off >>= 1)
#pragma unroll
            for (int h = 0; h < 4; ++h) cm[h] = fmaxf(cm[h], __shfl_xor(cm[h], off, 64));
        float scale[4];
#pragma unroll
        for (int h = 0; h < 4; ++h) {
            float nm = fmaxf(m[h], cm[h]);
            scale[h] = __expf(m[h] - nm);
            m[h] = nm;
            den[h] *= scale[h];
        }
        float sc = lane < 16 ? scale[0] : lane < 32 ? scale[1] : lane < 48 ? scale[2] : scale[3];
        acc0 *= sc; acc1 *= sc;
        float t[4];
#pragma unroll
        for (int h = 0; h < 4; ++h) {
            e[h] = valid ? __expf(e[h] - m[h]) : 0.f;
            t[h] = e[h];
        }
#pragma unroll
        for (int off = 32; off > 0; off >>= 1)
#pragma unroll
            for (int h = 0; h < 4; ++h) t[h] += __shfl_xor(t[h], off, 64);
#pragma unroll
        for (int h = 0; h < 4; ++h) den[h] += t[h];

        ssh[wid][lane] = s;
        *(float4*)&esh[wid][lane][0] = make_float4(e[0], e[1], e[2], e[3]);

        int cnt = min(64, end - cb);
#pragma unroll 2
        for (int jj = 0; jj < cnt; ++jj) {
            int   sj = ssh[wid][jj];
            float w  = esh[wid][jj][hsel];
            const __half2* hr = (const __half2*)(hx1h + (size_t)sj * C1);
            float2 vf = __half22float2(hr[lane]);
            acc0 += w * vf.x;
            acc1 += w * vf.y;
        }
    }

    float d = lane < 16 ? den[0] : lane < 32 ? den[1] : lane < 48 ? den[2] : den[3];
    float inv = 1.f / (d + 1e-16f);
    float2 bv = *(const float2*)(b1 + 2 * lane);
    float o0 = acc0 * inv + bv.x;
    float o1 = acc1 * inv + bv.y;
    o0 = o0 > 0.f ? o0 : (__expf(o0) - 1.f);   // ELU
    o1 = o1 > 0.f ? o1 : (__expf(o1) - 1.f);
    *(float2*)&x1[(size_t)n * C1 + 2 * lane] = make_float2(o0, o1);
}

// ---------------- layer 2 GEMM: hx2 = x1 @ W2 (+ logits), register-tiled ----------------
// BM=64, BN=64, BK=32; 256 threads; per-thread 4 rows x 4 cols.
__global__ __launch_bounds__(256) void gemm2_kernel(
        const float* __restrict__ x1, const float* __restrict__ W2,
        const float* __restrict__ attS, const float* __restrict__ attD,
        float* __restrict__ hx2, float* __restrict__ as2, float* __restrict__ ad2,
        int N) {
    __shared__ float xT[BK1][64 + 4];
    __shared__ float ws2[BK1][D2N];

    int tid = threadIdx.x;
    int tx  = tid & 15;          // col group: cols tx*4 .. tx*4+3
    int ty  = tid >> 4;          // row group: rows ty*4 .. ty*4+3
    int n0  = blockIdx.x * 64;

    float acc[4][4];
#pragma unroll
    for (int r = 0; r < 4; ++r)
#pragma unroll
        for (int c = 0; c < 4; ++c) acc[r][c] = 0.f;

    int lr = tid >> 2;                 // 0..63
    int lk = (tid & 3) * 4;            // 0,4,8,12
    int xrow = n0 + lr; if (xrow >= N) xrow = N - 1;
    const float* xptr = x1 + (size_t)xrow * C1;
    int kw = tid >> 4;                 // 0..15
    int cw = tx * 4;

    for (int k0 = 0; k0 < C1; k0 += BK1) {
        float4 a0 = *(const float4*)(xptr + k0 + lk);
        float4 a1 = *(const float4*)(xptr + k0 + lk + 16);
        float4 w0 = *(const float4*)(W2 + (size_t)(k0 + kw     ) * D2N + cw);
        float4 w1 = *(const float4*)(W2 + (size_t)(k0 + kw + 16) * D2N + cw);
        __syncthreads();
        xT[lk + 0][lr] = a0.x; xT[lk + 1][lr] = a0.y;
        xT[lk + 2][lr] = a0.z; xT[lk + 3][lr] = a0.w;
        xT[lk + 16][lr] = a1.x; xT[lk + 17][lr] = a1.y;
        xT[lk + 18][lr] = a1.z; xT[lk + 19][lr] = a1.w;
        *(float4*)&ws2[kw     ][cw] = w0;
        *(float4*)&ws2[kw + 16][cw] = w1;
        __syncthreads();
#pragma unroll
        for (int k = 0; k < BK1; ++k) {
            float4 xa = *(const float4*)&xT[k][ty * 4];
            float4 wv = *(const float4*)&ws2[k][tx * 4];
            float xr[4] = {xa.x, xa.y, xa.z, xa.w};
            float wc[4] = {wv.x, wv.y, wv.z, wv.w};
#pragma unroll
            for (int r = 0; r < 4; ++r)
#pragma unroll
                for (int c = 0; c < 4; ++c) acc[r][c] += xr[r] * wc[c];
        }
    }

    const float4 asv = *(const float4*)(attS + tx * 4);
    const float4 adv = *(const float4*)(attD + tx * 4);
#pragma unroll
    for (int r = 0; r < 4; ++r) {
        int n = n0 + ty * 4 + r;
        float ts = acc[r][0] * asv.x + acc[r][1] * asv.y + acc[r][2] * asv.z + acc[r][3] * asv.w;
        float td = acc[r][0] * adv.x + acc[r][1] * adv.y + acc[r][2] * adv.z + acc[r][3] * adv.w;
        ts += __shfl_xor(ts, 1); td += __shfl_xor(td, 1);
        ts += __shfl_xor(ts, 2); td += __shfl_xor(td, 2);
        ts += __shfl_xor(ts, 4); td += __shfl_xor(td, 4);
        ts += __shfl_xor(ts, 8); td += __shfl_xor(td, 8);
        if (n < N) {
            *(float4*)&hx2[(size_t)n * D2N + tx * 4] =
                make_float4(acc[r][0], acc[r][1], acc[r][2], acc[r][3]);
            if (tx == 0) { as2[n] = ts; ad2[n] = td; }
        }
    }
}

// ---------------- layer 2 aggregate: only last num_new nodes ----------------
__global__ void agg2_kernel(const int* __restrict__ edge_src, const int* __restrict__ offsets,
                            const float* __restrict__ as2, const float* __restrict__ ad2,
                            const float* __restrict__ hx2, const float* __restrict__ b2,
                            float* __restrict__ out, int N, int num_new) {
    __shared__ int   ssh[4][64];
    __shared__ float esh[4][64];
    int wid  = threadIdx.x >> 6;
    int w    = (blockIdx.x * blockDim.x + threadIdx.x) >> 6;
    int lane = threadIdx.x & 63;
    if (w >= num_new) return;
    int n = N - num_new + w;
    float adn = ad2[n];
    int beg = offsets[n], end = offsets[n + 1];

    float m = -INFINITY, den = 0.f, acc = 0.f;
    for (int cb = beg; cb < end; cb += 64) {
        int j = cb + lane;
        bool valid = j < end;
        int s = valid ? edge_src[j] : 0;
        float v = valid ? (as2[s] + adn) : -INFINITY;
        if (valid) v = v > 0.f ? v : 0.2f * v;
        float cm = v;
#pragma unroll
        for (int off = 32; off > 0; off >>= 1) cm = fmaxf(cm, __shfl_xor(cm, off, 64));
        float nm = fmaxf(m, cm);
        float scale = __expf(m - nm);
        m = nm;
        den *= scale;
        acc *= scale;
        float e = valid ? __expf(v - m) : 0.f;
        float t = e;
#pragma unroll
        for (int off = 32; off > 0; off >>= 1) t += __shfl_xor(t, off, 64);
        den += t;

        ssh[wid][lane] = s;
        esh[wid][lane] = e;

        int cnt = min(64, end - cb);
#pragma unroll 2
        for (int jj = 0; jj < cnt; ++jj) {
            int   sj = ssh[wid][jj];
            float wj = esh[wid][jj];
            acc += wj * hx2[(size_t)sj * D2N + lane];
        }
    }
    out[(size_t)w * D2N + lane] = acc / (den + 1e-16f) + b2[lane];
}

// ---------------- launch ----------------
extern "C" void kernel_launch(void* const* d_in, const int* in_sizes, int n_in,
                              void* d_out, int out_size, void* d_ws, size_t ws_size,
                              hipStream_t stream) {
    const float* x      = (const float*)d_in[0];
    const int*   src    = (const int*)d_in[1];
    const int*   dst    = (const int*)d_in[2];
    const float* W1     = (const float*)d_in[3];
    const float* attS1  = (const float*)d_in[4];
    const float* attD1  = (const float*)d_in[5];
    const float* b1     = (const float*)d_in[6];
    const float* W2     = (const float*)d_in[7];
    const float* attS2  = (const float*)d_in[8];
    const float* attD2  = (const float*)d_in[9];
    const float* b2     = (const float*)d_in[10];

    const int N = in_sizes[0] / F_IN;   // 50000
    const int E = in_sizes[1];          // 1000000
    const int num_new = out_size / D2N; // 10000
    const int ntiles = (N + SCAN_TILE - 1) / SCAN_TILE;   // 98
    const int ngemm  = (N + 63) / 64;                     // 782

    // workspace carve-up
    __half* hx1h = (__half*)d_ws;                        // N*128 halves
    float* x1  = (float*)(hx1h + (size_t)N * C1);        // N*128 f32
    float* hx2 = x1  + (size_t)N * C1;                   // N*64
    float* as1 = hx2 + (size_t)N * D2N;                  // N*4
    float* ad1 = as1 + (size_t)N * H1N;                  // N*4
    float* as2 = ad1 + (size_t)N * H1N;                  // N
    float* ad2 = as2 + N;                                // N
    int* counts    = (int*)(ad2 + N);                    // N
    int* offsets   = counts + N;                         // N+1
    int* tilesums  = offsets + N + 1;                    // 256
    int* tilebase  = tilesums + 256;                     // 256
    int* edge_src  = tilebase + 256;                     // E
    int* edge_rank = edge_src + E;                       // E

    float* out = (float*)d_out;

    hipLaunchKernelGGL(zero_ints, dim3(256), dim3(256), 0, stream, counts, N);
    hipLaunchKernelGGL(gemm1_count_kernel, dim3(ngemm + 512), dim3(256), 0, stream,
                       x, W1, attS1, attD1, hx1h, as1, ad1, N,
                       dst, counts, edge_rank, E, ngemm);
    hipLaunchKernelGGL(scan_partial, dim3(ntiles), dim3(SCAN_T), 0, stream, counts, tilesums, N);
    hipLaunchKernelGGL(scan_tops, dim3(1), dim3(SCAN_T), 0, stream, tilesums, tilebase, ntiles);
    hipLaunchKernelGGL(scan_final, dim3(ntiles), dim3(SCAN_T), 0, stream,
                       counts, tilebase, offsets, N, E);
    hipLaunchKernelGGL(scatter_rank, dim3(2048), dim3(256), 0, stream,
                       src, dst, edge_rank, offsets, edge_src, E, N);
    hipLaunchKernelGGL(agg1_kernel, dim3((N + 3) / 4), dim3(256), 0, stream,
                       edge_src, offsets, as1, ad1, hx1h, b1, x1, N);
    hipLaunchKernelGGL(gemm2_kernel, dim3((N + 63) / 64), dim3(256), 0, stream,
                       x1, W2, attS2, attD2, hx2, as2, ad2, N);
    hipLaunchKernelGGL(agg2_kernel, dim3((num_new + 3) / 4), dim3(256), 0, stream,
                       edge_src, offsets, as2, ad2, hx2, b2, out, N, num_new);
}

// Round 10
// 168.274 us; speedup vs baseline: 1.5743x; 1.0912x over previous
//
#include <hip/hip_runtime.h>
#include <hip/hip_fp16.h>
#include <math.h>

#define F_IN   256
#define C1     128   // H1*D1
#define H1N    4
#define D2N    64

#define SCAN_T    256
#define SCAN_TILE 512   // 2 elements per thread

#define BK1 32          // gemm K-tile

// ---------------- utility ----------------
__global__ void zero_ints(int* p, int n) {
    int i = blockIdx.x * blockDim.x + threadIdx.x;
    for (; i < n; i += gridDim.x * blockDim.x) p[i] = 0;
}

// ---------------- fused: layer-1 GEMM (blocks < ngemm) + edge count/rank (rest) ----------------
__global__ __launch_bounds__(256) void gemm1_count_kernel(
        const float* __restrict__ x, const float* __restrict__ W1,
        const float* __restrict__ attS, const float* __restrict__ attD,
        __half* __restrict__ hx1h, float* __restrict__ as1, float* __restrict__ ad1,
        int N,
        const int* __restrict__ dst, int* __restrict__ counts,
        int* __restrict__ edge_rank, int E, int ngemm) {
    if ((int)blockIdx.x >= ngemm) {
        int b  = blockIdx.x - ngemm;
        int nb = gridDim.x - ngemm;
        for (int i = b * blockDim.x + threadIdx.x; i < E; i += nb * blockDim.x)
            edge_rank[i] = atomicAdd(&counts[dst[i]], 1);
        return;
    }

    __shared__ float xT[BK1][64 + 4];
    __shared__ float ws[BK1][C1];

    int tid = threadIdx.x;
    int tx  = tid & 31;          // col group: cols tx*4 .. tx*4+3
    int ty  = tid >> 5;          // row group: rows ty*8 .. ty*8+7
    int n0  = blockIdx.x * 64;

    float acc[8][4];
#pragma unroll
    for (int r = 0; r < 8; ++r)
#pragma unroll
        for (int c = 0; c < 4; ++c) acc[r][c] = 0.f;

    int lr = tid >> 2;                 // 0..63
    int lk = (tid & 3) * 4;            // 0,4,8,12
    int xrow = n0 + lr; if (xrow >= N) xrow = N - 1;   // clamp (stores are guarded)
    const float* xptr = x + (size_t)xrow * F_IN;
    int kw = ty;
    int cw = tx * 4;

    for (int k0 = 0; k0 < F_IN; k0 += BK1) {
        float4 a0 = *(const float4*)(xptr + k0 + lk);
        float4 a1 = *(const float4*)(xptr + k0 + lk + 16);
        float4 w0 = *(const float4*)(W1 + (size_t)(k0 + kw     ) * C1 + cw);
        float4 w1 = *(const float4*)(W1 + (size_t)(k0 + kw +  8) * C1 + cw);
        float4 w2 = *(const float4*)(W1 + (size_t)(k0 + kw + 16) * C1 + cw);
        float4 w3 = *(const float4*)(W1 + (size_t)(k0 + kw + 24) * C1 + cw);
        __syncthreads();
        xT[lk + 0][lr] = a0.x; xT[lk + 1][lr] = a0.y;
        xT[lk + 2][lr] = a0.z; xT[lk + 3][lr] = a0.w;
        xT[lk + 16][lr] = a1.x; xT[lk + 17][lr] = a1.y;
        xT[lk + 18][lr] = a1.z; xT[lk + 19][lr] = a1.w;
        *(float4*)&ws[kw     ][cw] = w0;
        *(float4*)&ws[kw +  8][cw] = w1;
        *(float4*)&ws[kw + 16][cw] = w2;
        *(float4*)&ws[kw + 24][cw] = w3;
        __syncthreads();
#pragma unroll
        for (int k = 0; k < BK1; ++k) {
            float4 xa = *(const float4*)&xT[k][ty * 8];
            float4 xb = *(const float4*)&xT[k][ty * 8 + 4];
            float4 wv = *(const float4*)&ws[k][tx * 4];
            float xr[8] = {xa.x, xa.y, xa.z, xa.w, xb.x, xb.y, xb.z, xb.w};
            float wc[4] = {wv.x, wv.y, wv.z, wv.w};
#pragma unroll
            for (int r = 0; r < 8; ++r)
#pragma unroll
                for (int c = 0; c < 4; ++c) acc[r][c] += xr[r] * wc[c];
        }
    }

    const float4 asv = *(const float4*)(attS + tx * 4);
    const float4 adv = *(const float4*)(attD + tx * 4);
    int h = tx >> 3;
#pragma unroll
    for (int r = 0; r < 8; ++r) {
        int n = n0 + ty * 8 + r;
        float ts = acc[r][0] * asv.x + acc[r][1] * asv.y + acc[r][2] * asv.z + acc[r][3] * asv.w;
        float td = acc[r][0] * adv.x + acc[r][1] * adv.y + acc[r][2] * adv.z + acc[r][3] * adv.w;
        ts += __shfl_xor(ts, 1); td += __shfl_xor(td, 1);
        ts += __shfl_xor(ts, 2); td += __shfl_xor(td, 2);
        ts += __shfl_xor(ts, 4); td += __shfl_xor(td, 4);
        if (n < N) {
            __half2 p01 = __floats2half2_rn(acc[r][0], acc[r][1]);
            __half2 p23 = __floats2half2_rn(acc[r][2], acc[r][3]);
            *(__half2*)&hx1h[(size_t)n * C1 + tx * 4]     = p01;
            *(__half2*)&hx1h[(size_t)n * C1 + tx * 4 + 2] = p23;
            if ((tx & 7) == 0) {
                as1[n * H1N + h] = ts;
                ad1[n * H1N + h] = td;
            }
        }
    }
}

// ---------------- scan: counts -> offsets ----------------
__global__ void scan_partial(const int* __restrict__ counts, int* __restrict__ tilesums, int N) {
    __shared__ int red[SCAN_T];
    int t  = threadIdx.x;
    int i0 = blockIdx.x * SCAN_TILE + 2 * t;
    int s = 0;
    if (i0     < N) s += counts[i0];
    if (i0 + 1 < N) s += counts[i0 + 1];
    red[t] = s;
    __syncthreads();
    for (int off = SCAN_T / 2; off > 0; off >>= 1) {
        if (t < off) red[t] += red[t + off];
        __syncthreads();
    }
    if (t == 0) tilesums[blockIdx.x] = red[0];
}

__global__ void scan_tops(const int* __restrict__ tilesums, int* __restrict__ tilebase, int ntiles) {
    __shared__ int sh[SCAN_T];
    int t = threadIdx.x;
    int v = (t < ntiles) ? tilesums[t] : 0;
    sh[t] = v;
    __syncthreads();
    for (int off = 1; off < SCAN_T; off <<= 1) {
        int u = (t >= off) ? sh[t - off] : 0;
        __syncthreads();
        sh[t] += u;
        __syncthreads();
    }
    tilebase[t] = sh[t] - v;
}

__global__ void scan_final(const int* __restrict__ counts, const int* __restrict__ tilebase,
                           int* __restrict__ offsets, int N, int E) {
    __shared__ int sh[SCAN_T];
    int t  = threadIdx.x;
    int i0 = blockIdx.x * SCAN_TILE + 2 * t;
    int a   = (i0     < N) ? counts[i0]     : 0;
    int b   = (i0 + 1 < N) ? counts[i0 + 1] : 0;
    int tot = a + b;
    sh[t] = tot;
    __syncthreads();
    for (int off = 1; off < SCAN_T; off <<= 1) {
        int u = (t >= off) ? sh[t - off] : 0;
        __syncthreads();
        sh[t] += u;
        __syncthreads();
    }
    int excl = sh[t] - tot + tilebase[blockIdx.x];
    if (i0 < N)     offsets[i0]     = excl;
    if (i0 + 1 < N) offsets[i0 + 1] = excl + a;
    if (blockIdx.x == 0 && t == 0) offsets[N] = E;
}

// ---------------- atomic-free, XCD-binned scatter ----------------
__global__ void scatter_rank(const int* __restrict__ src, const int* __restrict__ dst,
                             const int* __restrict__ edge_rank, const int* __restrict__ offsets,
                             int* __restrict__ edge_src, int E, int N) {
    int grp  = blockIdx.x & 7;
    int gidx = blockIdx.x >> 3;
    int ngrp = gridDim.x >> 3;
    int lo = (int)((long long)N * grp / 8);
    int hi = (int)((long long)N * (grp + 1) / 8);
    for (int i = gidx * blockDim.x + threadIdx.x; i < E; i += ngrp * blockDim.x) {
        int d = dst[i];
        if (d >= lo && d < hi)
            edge_src[offsets[d] + edge_rank[i]] = src[i];
    }
}

// ---------------- layer 1 aggregate: no-max softmax (logits bounded; exp(v) safe in fp32) ----------------
// alpha = exp(v)/sum(exp(v)) is mathematically identical to the max-subtracted form.
// den accumulated per-lane, reduced once per node at the end.
__global__ void agg1_kernel(const int* __restrict__ edge_src, const int* __restrict__ offsets,
                            const float* __restrict__ as1, const float* __restrict__ ad1,
                            const __half* __restrict__ hx1h, const float* __restrict__ b1,
                            float* __restrict__ x1, int N) {
    __shared__ int   ssh[4][64];
    __shared__ float esh[4][64][4];
    int wid  = threadIdx.x >> 6;
    int n    = (blockIdx.x * blockDim.x + threadIdx.x) >> 6;
    int lane = threadIdx.x & 63;
    if (n >= N) return;
    int hsel = lane >> 4;                    // head of cols (2l, 2l+1)
    const float4 ad4 = *(const float4*)(ad1 + 4 * n);
    int beg = offsets[n], end = offsets[n + 1];

    float den[4] = {0.f, 0.f, 0.f, 0.f};
    float acc0 = 0.f, acc1 = 0.f;

    for (int cb = beg; cb < end; cb += 64) {
        int j = cb + lane;
        bool valid = j < end;
        int s = valid ? edge_src[j] : 0;
        float e0 = 0.f, e1 = 0.f, e2 = 0.f, e3 = 0.f;
        if (valid) {
            const float4 a4 = *(const float4*)(as1 + 4 * s);
            float v0 = a4.x + ad4.x, v1 = a4.y + ad4.y;
            float v2 = a4.z + ad4.z, v3 = a4.w + ad4.w;
            v0 = v0 > 0.f ? v0 : 0.2f * v0;
            v1 = v1 > 0.f ? v1 : 0.2f * v1;
            v2 = v2 > 0.f ? v2 : 0.2f * v2;
            v3 = v3 > 0.f ? v3 : 0.2f * v3;
            e0 = __expf(v0); e1 = __expf(v1);
            e2 = __expf(v2); e3 = __expf(v3);
            den[0] += e0; den[1] += e1; den[2] += e2; den[3] += e3;
        }
        ssh[wid][lane] = s;
        *(float4*)&esh[wid][lane][0] = make_float4(e0, e1, e2, e3);

        int cnt = min(64, end - cb);
#pragma unroll 4
        for (int jj = 0; jj < cnt; ++jj) {
            int   sj = ssh[wid][jj];
            float w  = esh[wid][jj][hsel];
            const __half2* hr = (const __half2*)(hx1h + (size_t)sj * C1);
            float2 vf = __half22float2(hr[lane]);
            acc0 += w * vf.x;
            acc1 += w * vf.y;
        }
    }

    // one reduction per node (unconditional shuffles — exec-mask safe)
#pragma unroll
    for (int off = 32; off > 0; off >>= 1)
#pragma unroll
        for (int h = 0; h < 4; ++h) den[h] += __shfl_xor(den[h], off, 64);

    float d = lane < 16 ? den[0] : lane < 32 ? den[1] : lane < 48 ? den[2] : den[3];
    float inv = 1.f / (d + 1e-16f);
    float2 bv = *(const float2*)(b1 + 2 * lane);
    float o0 = acc0 * inv + bv.x;
    float o1 = acc1 * inv + bv.y;
    o0 = o0 > 0.f ? o0 : (__expf(o0) - 1.f);   // ELU
    o1 = o1 > 0.f ? o1 : (__expf(o1) - 1.f);
    *(float2*)&x1[(size_t)n * C1 + 2 * lane] = make_float2(o0, o1);
}

// ---------------- layer 2 GEMM: hx2 = x1 @ W2 (+ logits), register-tiled ----------------
__global__ __launch_bounds__(256) void gemm2_kernel(
        const float* __restrict__ x1, const float* __restrict__ W2,
        const float* __restrict__ attS, const float* __restrict__ attD,
        float* __restrict__ hx2, float* __restrict__ as2, float* __restrict__ ad2,
        int N) {
    __shared__ float xT[BK1][64 + 4];
    __shared__ float ws2[BK1][D2N];

    int tid = threadIdx.x;
    int tx  = tid & 15;          // col group: cols tx*4 .. tx*4+3
    int ty  = tid >> 4;          // row group: rows ty*4 .. ty*4+3
    int n0  = blockIdx.x * 64;

    float acc[4][4];
#pragma unroll
    for (int r = 0; r < 4; ++r)
#pragma unroll
        for (int c = 0; c < 4; ++c) acc[r][c] = 0.f;

    int lr = tid >> 2;                 // 0..63
    int lk = (tid & 3) * 4;            // 0,4,8,12
    int xrow = n0 + lr; if (xrow >= N) xrow = N - 1;
    const float* xptr = x1 + (size_t)xrow * C1;
    int kw = tid >> 4;                 // 0..15
    int cw = tx * 4;

    for (int k0 = 0; k0 < C1; k0 += BK1) {
        float4 a0 = *(const float4*)(xptr + k0 + lk);
        float4 a1 = *(const float4*)(xptr + k0 + lk + 16);
        float4 w0 = *(const float4*)(W2 + (size_t)(k0 + kw     ) * D2N + cw);
        float4 w1 = *(const float4*)(W2 + (size_t)(k0 + kw + 16) * D2N + cw);
        __syncthreads();
        xT[lk + 0][lr] = a0.x; xT[lk + 1][lr] = a0.y;
        xT[lk + 2][lr] = a0.z; xT[lk + 3][lr] = a0.w;
        xT[lk + 16][lr] = a1.x; xT[lk + 17][lr] = a1.y;
        xT[lk + 18][lr] = a1.z; xT[lk + 19][lr] = a1.w;
        *(float4*)&ws2[kw     ][cw] = w0;
        *(float4*)&ws2[kw + 16][cw] = w1;
        __syncthreads();
#pragma unroll
        for (int k = 0; k < BK1; ++k) {
            float4 xa = *(const float4*)&xT[k][ty * 4];
            float4 wv = *(const float4*)&ws2[k][tx * 4];
            float xr[4] = {xa.x, xa.y, xa.z, xa.w};
            float wc[4] = {wv.x, wv.y, wv.z, wv.w};
#pragma unroll
            for (int r = 0; r < 4; ++r)
#pragma unroll
                for (int c = 0; c < 4; ++c) acc[r][c] += xr[r] * wc[c];
        }
    }

    const float4 asv = *(const float4*)(attS + tx * 4);
    const float4 adv = *(const float4*)(attD + tx * 4);
#pragma unroll
    for (int r = 0; r < 4; ++r) {
        int n = n0 + ty * 4 + r;
        float ts = acc[r][0] * asv.x + acc[r][1] * asv.y + acc[r][2] * asv.z + acc[r][3] * asv.w;
        float td = acc[r][0] * adv.x + acc[r][1] * adv.y + acc[r][2] * adv.z + acc[r][3] * adv.w;
        ts += __shfl_xor(ts, 1); td += __shfl_xor(td, 1);
        ts += __shfl_xor(ts, 2); td += __shfl_xor(td, 2);
        ts += __shfl_xor(ts, 4); td += __shfl_xor(td, 4);
        ts += __shfl_xor(ts, 8); td += __shfl_xor(td, 8);
        if (n < N) {
            *(float4*)&hx2[(size_t)n * D2N + tx * 4] =
                make_float4(acc[r][0], acc[r][1], acc[r][2], acc[r][3]);
            if (tx == 0) { as2[n] = ts; ad2[n] = td; }
        }
    }
}

// ---------------- layer 2 aggregate: no-max softmax, only last num_new nodes ----------------
__global__ void agg2_kernel(const int* __restrict__ edge_src, const int* __restrict__ offsets,
                            const float* __restrict__ as2, const float* __restrict__ ad2,
                            const float* __restrict__ hx2, const float* __restrict__ b2,
                            float* __restrict__ out, int N, int num_new) {
    __shared__ int   ssh[4][64];
    __shared__ float esh[4][64];
    int wid  = threadIdx.x >> 6;
    int w    = (blockIdx.x * blockDim.x + threadIdx.x) >> 6;
    int lane = threadIdx.x & 63;
    if (w >= num_new) return;
    int n = N - num_new + w;
    float adn = ad2[n];
    int beg = offsets[n], end = offsets[n + 1];

    float den = 0.f, acc = 0.f;
    for (int cb = beg; cb < end; cb += 64) {
        int j = cb + lane;
        bool valid = j < end;
        int s = valid ? edge_src[j] : 0;
        float e = 0.f;
        if (valid) {
            float v = as2[s] + adn;
            v = v > 0.f ? v : 0.2f * v;
            e = __expf(v);
            den += e;
        }
        ssh[wid][lane] = s;
        esh[wid][lane] = e;

        int cnt = min(64, end - cb);
#pragma unroll 4
        for (int jj = 0; jj < cnt; ++jj) {
            int   sj = ssh[wid][jj];
            float wj = esh[wid][jj];
            acc += wj * hx2[(size_t)sj * D2N + lane];
        }
    }
#pragma unroll
    for (int off = 32; off > 0; off >>= 1) den += __shfl_xor(den, off, 64);
    out[(size_t)w * D2N + lane] = acc / (den + 1e-16f) + b2[lane];
}

// ---------------- launch ----------------
extern "C" void kernel_launch(void* const* d_in, const int* in_sizes, int n_in,
                              void* d_out, int out_size, void* d_ws, size_t ws_size,
                              hipStream_t stream) {
    const float* x      = (const float*)d_in[0];
    const int*   src    = (const int*)d_in[1];
    const int*   dst    = (const int*)d_in[2];
    const float* W1     = (const float*)d_in[3];
    const float* attS1  = (const float*)d_in[4];
    const float* attD1  = (const float*)d_in[5];
    const float* b1     = (const float*)d_in[6];
    const float* W2     = (const float*)d_in[7];
    const float* attS2  = (const float*)d_in[8];
    const float* attD2  = (const float*)d_in[9];
    const float* b2     = (const float*)d_in[10];

    const int N = in_sizes[0] / F_IN;   // 50000
    const int E = in_sizes[1];          // 1000000
    const int num_new = out_size / D2N; // 10000
    const int ntiles = (N + SCAN_TILE - 1) / SCAN_TILE;   // 98
    const int ngemm  = (N + 63) / 64;                     // 782

    // workspace carve-up
    __half* hx1h = (__half*)d_ws;                        // N*128 halves
    float* x1  = (float*)(hx1h + (size_t)N * C1);        // N*128 f32
    float* hx2 = x1  + (size_t)N * C1;                   // N*64
    float* as1 = hx2 + (size_t)N * D2N;                  // N*4
    float* ad1 = as1 + (size_t)N * H1N;                  // N*4
    float* as2 = ad1 + (size_t)N * H1N;                  // N
    float* ad2 = as2 + N;                                // N
    int* counts    = (int*)(ad2 + N);                    // N
    int* offsets   = counts + N;                         // N+1
    int* tilesums  = offsets + N + 1;                    // 256
    int* tilebase  = tilesums + 256;                     // 256
    int* edge_src  = tilebase + 256;                     // E
    int* edge_rank = edge_src + E;                       // E

    float* out = (float*)d_out;

    hipLaunchKernelGGL(zero_ints, dim3(256), dim3(256), 0, stream, counts, N);
    hipLaunchKernelGGL(gemm1_count_kernel, dim3(ngemm + 512), dim3(256), 0, stream,
                       x, W1, attS1, attD1, hx1h, as1, ad1, N,
                       dst, counts, edge_rank, E, ngemm);
    hipLaunchKernelGGL(scan_partial, dim3(ntiles), dim3(SCAN_T), 0, stream, counts, tilesums, N);
    hipLaunchKernelGGL(scan_tops, dim3(1), dim3(SCAN_T), 0, stream, tilesums, tilebase, ntiles);
    hipLaunchKernelGGL(scan_final, dim3(ntiles), dim3(SCAN_T), 0, stream,
                       counts, tilebase, offsets, N, E);
    hipLaunchKernelGGL(scatter_rank, dim3(2048), dim3(256), 0, stream,
                       src, dst, edge_rank, offsets, edge_src, E, N);
    hipLaunchKernelGGL(agg1_kernel, dim3((N + 3) / 4), dim3(256), 0, stream,
                       edge_src, offsets, as1, ad1, hx1h, b1, x1, N);
    hipLaunchKernelGGL(gemm2_kernel, dim3((N + 63) / 64), dim3(256), 0, stream,
                       x1, W2, attS2, attD2, hx2, as2, ad2, N);
    hipLaunchKernelGGL(agg2_kernel, dim3((num_new + 3) / 4), dim3(256), 0, stream,
                       edge_src, offsets, as2, ad2, hx2, b2, out, N, num_new);
}